// Round 1
// baseline (409.532 us; speedup 1.0000x reference)
//
#include <hip/hip_runtime.h>

#define NDON 32768
#define CAP  4096
#define K    16

__device__ __forceinline__ bool is_inf_f(float x) {
    return ((__float_as_uint(x) & 0x7fffffffu) == 0x7f800000u);
}
__device__ __forceinline__ bool is_nan_f(float x) {
    return ((__float_as_uint(x) & 0x7fffffffu) > 0x7f800000u);
}

__global__ __launch_bounds__(256) void calc_impute_kernel(
    const float* __restrict__ dist,
    const float* __restrict__ fitcol,
    const int*  __restrict__ maskcol,
    float* __restrict__ out)
{
    __shared__ int   cnt;
    __shared__ float cv[CAP];
    __shared__ int   ci[CAP];
    __shared__ float wredv[4];
    __shared__ int   wredi[4];
    __shared__ int   wredp[4];
    __shared__ int   sel_idx[K];

    const int tid = threadIdx.x;
    const float* row = dist + (size_t)blockIdx.x * NDON;

    // ---- Phase 1: threshold-filter scan (single streaming read of the row) ----
    // Uniform[0,1) data: 16th smallest ~ 4.9e-4, so thr=0.004 keeps ~131
    // candidates (P(<16) ~ 1e-24). Adaptive rescan fallback for robustness.
    float thr = 0.004f;
    int n = 0;
    for (int attempt = 0; attempt < 20; ++attempt) {
        if (tid == 0) cnt = 0;
        __syncthreads();
        for (int it = 0; it < NDON / 1024; ++it) {
            const int base = it * 1024 + tid * 4;
            const float4 v4 = *reinterpret_cast<const float4*>(row + base);
            const float vals[4] = {v4.x, v4.y, v4.z, v4.w};
            #pragma unroll
            for (int j = 0; j < 4; ++j) {
                float sv = vals[j];
                if (is_nan_f(sv)) sv = 1.0e10f;   // nan_to_num before top-k
                if (sv < thr) {
                    int p = atomicAdd(&cnt, 1);
                    if (p < CAP) { cv[p] = sv; ci[p] = base + j; }
                }
            }
        }
        __syncthreads();
        n = cnt;
        if (n >= K && n <= CAP) break;
        thr = (n < K) ? thr * 8.0f : thr * 0.125f;
        __syncthreads();  // all reads of cnt done before next reset
    }
    if (n > CAP) n = CAP;

    // ---- Phase 2: 16 block-wide argmin extractions, tie-break (val, idx) ----
    // Matches jax.lax.top_k: ascending value, lower index wins ties.
    for (int s = 0; s < K; ++s) {
        float bv = 3.0e38f;
        int   bi = 0x7FFFFFFF;
        int   bp = -1;
        for (int p = tid; p < n; p += 256) {
            const float v = cv[p];
            const int   i = ci[p];
            if (v < bv || (v == bv && i < bi)) { bv = v; bi = i; bp = p; }
        }
        #pragma unroll
        for (int o = 32; o >= 1; o >>= 1) {
            const float ov = __shfl_down(bv, o);
            const int   oi = __shfl_down(bi, o);
            const int   op = __shfl_down(bp, o);
            if (ov < bv || (ov == bv && oi < bi)) { bv = ov; bi = oi; bp = op; }
        }
        if ((tid & 63) == 0) {
            const int w = tid >> 6;
            wredv[w] = bv; wredi[w] = bi; wredp[w] = bp;
        }
        __syncthreads();
        if (tid == 0) {
            #pragma unroll
            for (int w = 1; w < 4; ++w) {
                if (wredv[w] < bv || (wredv[w] == bv && wredi[w] < bi)) {
                    bv = wredv[w]; bi = wredi[w]; bp = wredp[w];
                }
            }
            sel_idx[s] = bi;
            if (bp >= 0) cv[bp] = 3.0e38f;   // remove winner
        }
        __syncthreads();
    }

    // ---- Phase 3: epilogue — weights / masks / weighted mean (exact ref semantics) ----
    if (tid == 0) {
        float dsel[K];
        #pragma unroll
        for (int s = 0; s < K; ++s) dsel[s] = row[sel_idx[s]];  // ORIGINAL distances

        bool infrow = false;
        #pragma unroll
        for (int s = 0; s < K; ++s) {
            const float wt = 1.0f / dsel[s];
            if (is_inf_f(wt)) infrow = true;
        }

        float wsum = 0.0f, dsum = 0.0f;
        #pragma unroll
        for (int s = 0; s < K; ++s) {
            const float wt = 1.0f / dsel[s];
            float wm;
            if (infrow) wm = is_inf_f(wt) ? 1.0f : 0.0f;   // inf_mask row
            else        wm = is_nan_f(wt) ? 0.0f : wt;     // nan->0
            const int   idx = sel_idx[s];
            const float dm  = 1.0f - (float)maskcol[idx];  // 1 - mask
            const float nw  = dm * wm;
            wsum += nw;
            dsum += fitcol[idx] * nw;
        }
        const float div = (wsum == 0.0f) ? 1.0f : wsum;
        out[blockIdx.x] = dsum / div;
    }
}

extern "C" void kernel_launch(void* const* d_in, const int* in_sizes, int n_in,
                              void* d_out, int out_size, void* d_ws, size_t ws_size,
                              hipStream_t stream) {
    const float* dist    = (const float*)d_in[0];
    // d_in[1] = n_neighbors (scalar 16, fixed by the reference)
    const float* fitcol  = (const float*)d_in[2];
    const int*   maskcol = (const int*)d_in[3];
    float* out = (float*)d_out;

    calc_impute_kernel<<<dim3(out_size), dim3(256), 0, stream>>>(dist, fitcol, maskcol, out);
}

// Round 2
// 239.292 us; speedup vs baseline: 1.7114x; 1.7114x over previous
//
#include <hip/hip_runtime.h>

#define NDON 32768
#define CAP  1024
#define K    16

__device__ __forceinline__ bool is_inf_f(float x) {
    return ((__float_as_uint(x) & 0x7fffffffu) == 0x7f800000u);
}
__device__ __forceinline__ bool is_nan_f(float x) {
    return ((__float_as_uint(x) & 0x7fffffffu) > 0x7f800000u);
}

__global__ __launch_bounds__(256, 8) void calc_impute_kernel(
    const float* __restrict__ dist,
    const float* __restrict__ fitcol,
    const int*  __restrict__ maskcol,
    float* __restrict__ out)
{
    __shared__ int   cnt;
    __shared__ float cv[CAP];
    __shared__ int   ci[CAP];
    __shared__ float wredv[4];
    __shared__ int   wredi[4];
    __shared__ int   wredp[4];
    __shared__ int   sel_idx[K];

    const int tid = threadIdx.x;
    const float* row = dist + (size_t)blockIdx.x * NDON;
    const float4* rp = reinterpret_cast<const float4*>(row) + tid;

    // ---- Phase 1: threshold-filter scan (one streaming read, 4 loads in flight) ----
    // Uniform[0,1): 16th smallest ~4.9e-4; thr=0.004 keeps ~131 candidates
    // (P(<16) ~ 1e-24, P(>1024) astronomically small). Adaptive rescan fallback.
    // NaN fast path: IEEE compare (v<thr) is false for NaN, which matches
    // nan_to_num(1e10) semantics unless thr>1e10 (uniform flag, fallback-only).
    float thr = 0.004f;
    int n = 0;
    for (int attempt = 0; attempt < 20; ++attempt) {
        const bool nanpass = (thr > 1.0e10f);
        if (tid == 0) cnt = 0;
        __syncthreads();
        for (int it = 0; it < 8; ++it) {
            float4 v[4];
            #pragma unroll
            for (int u = 0; u < 4; ++u) v[u] = rp[it * 1024 + u * 256];
            #pragma unroll
            for (int u = 0; u < 4; ++u) {
                const float4 q = v[u];
                bool p0 = q.x < thr, p1 = q.y < thr, p2 = q.z < thr, p3 = q.w < thr;
                if (nanpass) {  // wave-uniform, never taken on sane data
                    p0 |= is_nan_f(q.x); p1 |= is_nan_f(q.y);
                    p2 |= is_nan_f(q.z); p3 |= is_nan_f(q.w);
                }
                if (p0 | p1 | p2 | p3) {
                    const int base = it * 4096 + u * 1024 + tid * 4;
                    const float vals[4] = {q.x, q.y, q.z, q.w};
                    const bool  ps[4]   = {p0, p1, p2, p3};
                    #pragma unroll
                    for (int j = 0; j < 4; ++j) {
                        if (ps[j]) {
                            const float sv = is_nan_f(vals[j]) ? 1.0e10f : vals[j];
                            const int p = atomicAdd(&cnt, 1);
                            if (p < CAP) { cv[p] = sv; ci[p] = base + j; }
                        }
                    }
                }
            }
        }
        __syncthreads();
        n = cnt;
        if (n >= K && n <= CAP) break;
        thr = (n < K) ? thr * 8.0f : thr * 0.125f;
        __syncthreads();  // all reads of cnt done before next reset
    }
    if (n > CAP) n = CAP;

    // ---- Phase 2: 16 block-wide argmin extractions, tie-break (val, idx) ----
    // Matches jax.lax.top_k: ascending value, lower index wins ties.
    for (int s = 0; s < K; ++s) {
        float bv = 3.0e38f;
        int   bi = 0x7FFFFFFF;
        int   bp = -1;
        for (int p = tid; p < n; p += 256) {
            const float v = cv[p];
            const int   i = ci[p];
            if (v < bv || (v == bv && i < bi)) { bv = v; bi = i; bp = p; }
        }
        #pragma unroll
        for (int o = 32; o >= 1; o >>= 1) {
            const float ov = __shfl_down(bv, o);
            const int   oi = __shfl_down(bi, o);
            const int   op = __shfl_down(bp, o);
            if (ov < bv || (ov == bv && oi < bi)) { bv = ov; bi = oi; bp = op; }
        }
        if ((tid & 63) == 0) {
            const int w = tid >> 6;
            wredv[w] = bv; wredi[w] = bi; wredp[w] = bp;
        }
        __syncthreads();
        if (tid == 0) {
            #pragma unroll
            for (int w = 1; w < 4; ++w) {
                if (wredv[w] < bv || (wredv[w] == bv && wredi[w] < bi)) {
                    bv = wredv[w]; bi = wredi[w]; bp = wredp[w];
                }
            }
            sel_idx[s] = bi;
            if (bp >= 0) cv[bp] = 3.0e38f;   // remove winner
        }
        __syncthreads();
    }

    // ---- Phase 3: epilogue — weights / masks / weighted mean (exact ref semantics) ----
    if (tid == 0) {
        float dsel[K];
        #pragma unroll
        for (int s = 0; s < K; ++s) dsel[s] = row[sel_idx[s]];  // ORIGINAL distances

        bool infrow = false;
        #pragma unroll
        for (int s = 0; s < K; ++s) {
            const float wt = 1.0f / dsel[s];
            if (is_inf_f(wt)) infrow = true;
        }

        float wsum = 0.0f, dsum = 0.0f;
        #pragma unroll
        for (int s = 0; s < K; ++s) {
            const float wt = 1.0f / dsel[s];
            float wm;
            if (infrow) wm = is_inf_f(wt) ? 1.0f : 0.0f;   // inf_mask row
            else        wm = is_nan_f(wt) ? 0.0f : wt;     // nan->0
            const int   idx = sel_idx[s];
            const float dm  = 1.0f - (float)maskcol[idx];  // 1 - mask
            const float nw  = dm * wm;
            wsum += nw;
            dsum += fitcol[idx] * nw;
        }
        const float div = (wsum == 0.0f) ? 1.0f : wsum;
        out[blockIdx.x] = dsum / div;
    }
}

extern "C" void kernel_launch(void* const* d_in, const int* in_sizes, int n_in,
                              void* d_out, int out_size, void* d_ws, size_t ws_size,
                              hipStream_t stream) {
    const float* dist    = (const float*)d_in[0];
    // d_in[1] = n_neighbors (scalar 16, fixed by the reference)
    const float* fitcol  = (const float*)d_in[2];
    const int*   maskcol = (const int*)d_in[3];
    float* out = (float*)d_out;

    calc_impute_kernel<<<dim3(out_size), dim3(256), 0, stream>>>(dist, fitcol, maskcol, out);
}

// Round 4
// 195.331 us; speedup vs baseline: 2.0966x; 1.2251x over previous
//
#include <hip/hip_runtime.h>

#define NDON 32768
#define CAP  1024
#define K    16
#define BIGV 3.0e38f
#define IMAX 0x7FFFFFFF

__device__ __forceinline__ bool is_inf_f(float x) {
    return ((__float_as_uint(x) & 0x7fffffffu) == 0x7f800000u);
}
__device__ __forceinline__ bool is_nan_f(float x) {
    return ((__float_as_uint(x) & 0x7fffffffu) > 0x7f800000u);
}

__global__ __launch_bounds__(256, 8) void calc_impute_kernel(
    const float* __restrict__ dist,
    const float* __restrict__ fitcol,
    const int*  __restrict__ maskcol,
    float* __restrict__ out)
{
    __shared__ int   cnt;
    __shared__ float cv[CAP];
    __shared__ int   ci[CAP];

    const int tid = threadIdx.x;
    const float* row = dist + (size_t)blockIdx.x * NDON;
    const float4* rp = reinterpret_cast<const float4*>(row) + tid;

    // ---- Phase 1: threshold-filter scan (one streaming read, 4 loads in flight) ----
    // Uniform[0,1): 16th smallest ~4.9e-4; thr=0.002 keeps E~65.5 candidates
    // (P(<16) ~ 3e-10/row; rescan fallback guarantees correctness regardless).
    // NaN fast path: IEEE (v<thr) is false for NaN == nan_to_num(1e10) semantics
    // unless thr>1e10 (wave-uniform flag, reachable only via fallback escalation).
    float thr = 0.002f;
    int n = 0;
    for (int attempt = 0; attempt < 20; ++attempt) {
        const bool nanpass = (thr > 1.0e10f);
        if (tid == 0) cnt = 0;
        __syncthreads();
        for (int it = 0; it < 8; ++it) {
            float4 v[4];
            #pragma unroll
            for (int u = 0; u < 4; ++u) v[u] = rp[it * 1024 + u * 256];
            #pragma unroll
            for (int u = 0; u < 4; ++u) {
                const float4 q = v[u];
                bool p0 = q.x < thr, p1 = q.y < thr, p2 = q.z < thr, p3 = q.w < thr;
                if (nanpass) {  // wave-uniform, never taken on sane data
                    p0 |= is_nan_f(q.x); p1 |= is_nan_f(q.y);
                    p2 |= is_nan_f(q.z); p3 |= is_nan_f(q.w);
                }
                if (p0 | p1 | p2 | p3) {
                    const int base = it * 4096 + u * 1024 + tid * 4;
                    const float vals[4] = {q.x, q.y, q.z, q.w};
                    const bool  ps[4]   = {p0, p1, p2, p3};
                    #pragma unroll
                    for (int j = 0; j < 4; ++j) {
                        if (ps[j]) {
                            const float sv = is_nan_f(vals[j]) ? 1.0e10f : vals[j];
                            const int p = atomicAdd(&cnt, 1);
                            if (p < CAP) { cv[p] = sv; ci[p] = base + j; }
                        }
                    }
                }
            }
        }
        __syncthreads();   // cv/ci visible to all; cnt final
        n = cnt;
        if (n >= K && n <= CAP) break;
        thr = (n < K) ? thr * 8.0f : thr * 0.125f;
        __syncthreads();   // all reads of cnt done before next reset
    }
    if (n > CAP) n = CAP;

    // ---- Waves 1-3 retire: frees SIMD slots for the next block's streaming ----
    if (tid >= 64) return;
    const int lane = tid;

    // ---- Phase 2: wave 0 alone, 16 argmin extractions, zero barriers ----
    // Register-cache first 128 candidates (2 slots/lane); LDS slow path for
    // n>128 (fallback-only). Tie-break (value, index) == jax.lax.top_k.
    float rv0 = (lane < n)      ? cv[lane]      : BIGV;
    int   ri0 = (lane < n)      ? ci[lane]      : IMAX;
    float rv1 = (lane + 64 < n) ? cv[lane + 64] : BIGV;
    int   ri1 = (lane + 64 < n) ? ci[lane + 64] : IMAX;
    const bool big = (n > 128);

    int my_sel = 0;
    #pragma unroll
    for (int s = 0; s < K; ++s) {
        float bv; int bi; int bp = -1;
        if (rv1 < rv0 || (rv1 == rv0 && ri1 < ri0)) { bv = rv1; bi = ri1; }
        else                                        { bv = rv0; bi = ri0; }
        if (big) {
            for (int p = 128 + lane; p < n; p += 64) {
                const float v = cv[p]; const int i = ci[p];
                if (v < bv || (v == bv && i < bi)) { bv = v; bi = i; bp = p; }
            }
        }
        #pragma unroll
        for (int o = 1; o < 64; o <<= 1) {
            const float ov = __shfl_xor(bv, o);
            const int   oi = __shfl_xor(bi, o);
            const int   op = __shfl_xor(bp, o);
            if (ov < bv || (ov == bv && oi < bi)) { bv = ov; bi = oi; bp = op; }
        }
        // all lanes agree on winner (bv, bi, bp); remove it
        if (ri0 == bi) { rv0 = BIGV; ri0 = IMAX; }
        if (ri1 == bi) { rv1 = BIGV; ri1 = IMAX; }
        if (big && bp >= 0 && lane == 0) { cv[bp] = BIGV; ci[bp] = IMAX; }
        if (lane == s) my_sel = bi;
    }

    // ---- Phase 3: parallel epilogue, lanes 0..15 each own one donor ----
    const bool act = (lane < K);
    const int  idx = my_sel;
    const float d  = act ? row[idx] : 1.0f;          // ORIGINAL distance
    const float wt = 1.0f / d;
    const bool  winf = act && is_inf_f(wt);
    const unsigned long long m = __ballot(winf);
    const bool infrow = (m != 0ull);
    float wm = infrow ? (winf ? 1.0f : 0.0f)          // inf_mask row
                      : (is_nan_f(wt) ? 0.0f : wt);   // nan -> 0
    if (!act) wm = 0.0f;
    const float dm = act ? 1.0f - (float)maskcol[idx] : 0.0f;  // 1 - mask
    const float fv = act ? fitcol[idx] : 0.0f;
    const float nw = dm * wm;
    float ws = nw, ds = fv * nw;
    #pragma unroll
    for (int o = 1; o < K; o <<= 1) {
        ws += __shfl_xor(ws, o);
        ds += __shfl_xor(ds, o);
    }
    if (lane == 0) out[blockIdx.x] = ds / ((ws == 0.0f) ? 1.0f : ws);
}

extern "C" void kernel_launch(void* const* d_in, const int* in_sizes, int n_in,
                              void* d_out, int out_size, void* d_ws, size_t ws_size,
                              hipStream_t stream) {
    const float* dist    = (const float*)d_in[0];
    // d_in[1] = n_neighbors (scalar 16, fixed by the reference)
    const float* fitcol  = (const float*)d_in[2];
    const int*   maskcol = (const int*)d_in[3];
    float* out = (float*)d_out;

    calc_impute_kernel<<<dim3(out_size), dim3(256), 0, stream>>>(dist, fitcol, maskcol, out);
}

// Round 5
// 193.987 us; speedup vs baseline: 2.1111x; 1.0069x over previous
//
#include <hip/hip_runtime.h>

#define NDON 32768
#define CAP  1024
#define K    16
#define BIGV 3.0e38f
#define IMAX 0x7FFFFFFF

__device__ __forceinline__ bool is_inf_f(float x) {
    return ((__float_as_uint(x) & 0x7fffffffu) == 0x7f800000u);
}
__device__ __forceinline__ bool is_nan_f(float x) {
    return ((__float_as_uint(x) & 0x7fffffffu) > 0x7f800000u);
}

__global__ __launch_bounds__(256, 8) void calc_impute_kernel(
    const float* __restrict__ dist,
    const float* __restrict__ fitcol,
    const int*  __restrict__ maskcol,
    float* __restrict__ out)
{
    __shared__ int   cnt;
    __shared__ float cv[CAP];
    __shared__ int   ci[CAP];

    const int tid = threadIdx.x;
    const float* row = dist + (size_t)blockIdx.x * NDON;
    const float4* rp = reinterpret_cast<const float4*>(row) + tid;

    // ---- Phase 1: threshold-filter scan, 1-group-ahead software pipeline ----
    // Uniform[0,1): 16th smallest ~4.9e-4; thr=0.002 keeps E~65.5 candidates
    // (P(<16) ~ 3e-10/row; rescan fallback guarantees correctness regardless).
    // NaN fast path: IEEE (v<thr) is false for NaN == nan_to_num(1e10) semantics
    // unless thr>1e10 (wave-uniform flag, reachable only via fallback escalation).
    // Pipeline: group it+1's 4 loads are issued BEFORE group it is consumed, so
    // vmcnt never drains to 0 mid-row (no full-HBM-latency bubble per group).
    float thr = 0.002f;
    int n = 0;
    for (int attempt = 0; attempt < 20; ++attempt) {
        const bool nanpass = (thr > 1.0e10f);
        if (tid == 0) cnt = 0;
        __syncthreads();
        float4 v[4];
        #pragma unroll
        for (int u = 0; u < 4; ++u) v[u] = rp[u * 256];
        for (int it = 0; it < 8; ++it) {
            float4 w[4];
            if (it < 7) {
                #pragma unroll
                for (int u = 0; u < 4; ++u) w[u] = rp[(it + 1) * 1024 + u * 256];
            }
            #pragma unroll
            for (int u = 0; u < 4; ++u) {
                const float4 q = v[u];
                bool p0 = q.x < thr, p1 = q.y < thr, p2 = q.z < thr, p3 = q.w < thr;
                if (nanpass) {  // wave-uniform, never taken on sane data
                    p0 |= is_nan_f(q.x); p1 |= is_nan_f(q.y);
                    p2 |= is_nan_f(q.z); p3 |= is_nan_f(q.w);
                }
                if (p0 | p1 | p2 | p3) {
                    const int base = it * 4096 + u * 1024 + tid * 4;
                    const float vals[4] = {q.x, q.y, q.z, q.w};
                    const bool  ps[4]   = {p0, p1, p2, p3};
                    #pragma unroll
                    for (int j = 0; j < 4; ++j) {
                        if (ps[j]) {
                            const float sv = is_nan_f(vals[j]) ? 1.0e10f : vals[j];
                            const int p = atomicAdd(&cnt, 1);
                            if (p < CAP) { cv[p] = sv; ci[p] = base + j; }
                        }
                    }
                }
            }
            if (it < 7) {
                #pragma unroll
                for (int u = 0; u < 4; ++u) v[u] = w[u];
            }
        }
        __syncthreads();   // cv/ci visible to all; cnt final
        n = cnt;
        if (n >= K && n <= CAP) break;
        thr = (n < K) ? thr * 8.0f : thr * 0.125f;
        __syncthreads();   // all reads of cnt done before next reset
    }
    if (n > CAP) n = CAP;
    // thr unchanged since the successful scan -> this flags whether NaNs could
    // have been inserted (sv substitution), i.e. whether cv[] != original value.
    const bool scan_nanpass = (thr > 1.0e10f);

    // ---- Waves 1-3 retire: frees SIMD slots for the next block's streaming ----
    if (tid >= 64) return;
    const int lane = tid;

    // ---- Phase 2: wave 0 alone, 16 argmin extractions, zero barriers ----
    // Register-cache first 128 candidates (2 slots/lane); LDS slow path for
    // n>128 (fallback-only). Tie-break (value, index) == jax.lax.top_k.
    float rv0 = (lane < n)      ? cv[lane]      : BIGV;
    int   ri0 = (lane < n)      ? ci[lane]      : IMAX;
    float rv1 = (lane + 64 < n) ? cv[lane + 64] : BIGV;
    int   ri1 = (lane + 64 < n) ? ci[lane + 64] : IMAX;
    const bool big = (n > 128);

    int   my_sel = 0;
    float my_val = 1.0f;
    #pragma unroll
    for (int s = 0; s < K; ++s) {
        float bv; int bi; int bp = -1;
        if (rv1 < rv0 || (rv1 == rv0 && ri1 < ri0)) { bv = rv1; bi = ri1; }
        else                                        { bv = rv0; bi = ri0; }
        if (big) {
            for (int p = 128 + lane; p < n; p += 64) {
                const float v = cv[p]; const int i = ci[p];
                if (v < bv || (v == bv && i < bi)) { bv = v; bi = i; bp = p; }
            }
        }
        #pragma unroll
        for (int o = 1; o < 64; o <<= 1) {
            const float ov = __shfl_xor(bv, o);
            const int   oi = __shfl_xor(bi, o);
            const int   op = __shfl_xor(bp, o);
            if (ov < bv || (ov == bv && oi < bi)) { bv = ov; bi = oi; bp = op; }
        }
        // all lanes agree on winner (bv, bi, bp); remove it
        if (ri0 == bi) { rv0 = BIGV; ri0 = IMAX; }
        if (ri1 == bi) { rv1 = BIGV; ri1 = IMAX; }
        if (big && bp >= 0 && lane == 0) { cv[bp] = BIGV; ci[bp] = IMAX; }
        if (lane == s) { my_sel = bi; my_val = bv; }
    }

    // ---- Phase 3: parallel epilogue, lanes 0..15 each own one donor ----
    // Fast path: cv stored the ORIGINAL value (NaN can't pass thr<=1e10), so
    // my_val == row[my_sel] and no global re-gather of the evicted row needed.
    const bool act = (lane < K);
    const int  idx = my_sel;
    float d = my_val;
    if (scan_nanpass && act) d = row[idx];  // rare: sv substitution was active
    const float wt = 1.0f / d;
    const bool  winf = act && is_inf_f(wt);
    const unsigned long long m = __ballot(winf);
    const bool infrow = (m != 0ull);
    float wm = infrow ? (winf ? 1.0f : 0.0f)          // inf_mask row
                      : (is_nan_f(wt) ? 0.0f : wt);   // nan -> 0
    if (!act) wm = 0.0f;
    const float dm = act ? 1.0f - (float)maskcol[idx] : 0.0f;  // 1 - mask
    const float fv = act ? fitcol[idx] : 0.0f;
    const float nw = dm * wm;
    float ws = nw, ds = fv * nw;
    #pragma unroll
    for (int o = 1; o < K; o <<= 1) {
        ws += __shfl_xor(ws, o);
        ds += __shfl_xor(ds, o);
    }
    if (lane == 0) out[blockIdx.x] = ds / ((ws == 0.0f) ? 1.0f : ws);
}

extern "C" void kernel_launch(void* const* d_in, const int* in_sizes, int n_in,
                              void* d_out, int out_size, void* d_ws, size_t ws_size,
                              hipStream_t stream) {
    const float* dist    = (const float*)d_in[0];
    // d_in[1] = n_neighbors (scalar 16, fixed by the reference)
    const float* fitcol  = (const float*)d_in[2];
    const int*   maskcol = (const int*)d_in[3];
    float* out = (float*)d_out;

    calc_impute_kernel<<<dim3(out_size), dim3(256), 0, stream>>>(dist, fitcol, maskcol, out);
}